// Round 7
// baseline (1216.855 us; speedup 1.0000x reference)
//
#include <hip/hip_runtime.h>

#define B_ 32
#define T_ 120
#define E_ 256
#define H_ 512
#define NSPAN 36960   // B_ * 1155

typedef __attribute__((ext_vector_type(8))) short short8;
typedef __attribute__((ext_vector_type(4))) short sshort4;
typedef __attribute__((ext_vector_type(4))) float f32x4;
typedef __attribute__((ext_vector_type(4))) unsigned int u32x4;
typedef unsigned long long ull;

__device__ __forceinline__ short f2bf(float x) {
    union { float f; unsigned u; } v; v.f = x;
    unsigned r = v.u + 0x7fffu + ((v.u >> 16) & 1u);
    return (short)(r >> 16);
}
__device__ __forceinline__ float bf2f(unsigned short x) {
    union { unsigned u; float f; } v; v.u = ((unsigned)x) << 16;
    return v.f;
}

// coherent (IC-visible) 16B load: base reg-pair + compile-time byte offset
#define LDX4(dst, base, OFFS) \
    asm volatile("global_load_dwordx4 %0, %1, off offset:" OFFS " sc0 sc1" \
                 : "=v"(dst) : "v"(base))

// ---------------- gather tokens -> x bf16 (row m = t*32 + b) ----------------
__global__ void k_gather(const int* __restrict__ tokens, const float* __restrict__ emb,
                         short* __restrict__ xbf) {
    int m = blockIdx.x;              // 0..3839, m = t*32+b
    int t = m >> 5, b = m & 31;
    int tok = tokens[b * T_ + t];
    int e = threadIdx.x;             // 256
    xbf[(size_t)m * E_ + e] = f2bf(emb[(size_t)tok * E_ + e]);
}

// ---------------- fp32 -> bf16 convert ----------------
__global__ void k_convert(const float* __restrict__ src, short* __restrict__ dst, int n8) {
    int i = blockIdx.x * blockDim.x + threadIdx.x;
    if (i >= n8) return;
    const float4* s4 = (const float4*)src + (size_t)i * 2;
    float4 a = s4[0], b = s4[1];
    short8 o;
    o[0]=f2bf(a.x); o[1]=f2bf(a.y); o[2]=f2bf(a.z); o[3]=f2bf(a.w);
    o[4]=f2bf(b.x); o[5]=f2bf(b.y); o[6]=f2bf(b.z); o[7]=f2bf(b.w);
    *(short8*)(dst + (size_t)i * 8) = o;
}

__global__ void k_biascomb(const float* __restrict__ bf1, const float* __restrict__ bf2,
                           const float* __restrict__ bb1, const float* __restrict__ bb2,
                           float* __restrict__ out) {
    int i = blockIdx.x * 256 + threadIdx.x;   // 4096
    out[i] = (i < 2048) ? (bf1[i] + bf2[i]) : (bb1[i - 2048] + bb2[i - 2048]);
}

// ---------------- generic bf16 MFMA GEMM: out = A(MxK) @ W(NxK)^T + bias ----------------
template <int EPI>
__global__ void __launch_bounds__(256) k_gemm(const short* __restrict__ A,
                                              const short* __restrict__ W,
                                              const float* __restrict__ bias,
                                              float* __restrict__ outF,
                                              short* __restrict__ outB,
                                              int N, int K) {
    int w = threadIdx.x >> 6, l = threadIdx.x & 63;
    int la = l & 15, lb = l >> 4;
    int m0 = blockIdx.x * 64 + w * 16;
    int nb = blockIdx.y * 64;
    const short* Ap = A + (size_t)(m0 + la) * K + lb * 8;
    const short* Wp = W + (size_t)(nb + la) * K + lb * 8;
    f32x4 acc0 = {0.f,0.f,0.f,0.f}, acc1 = acc0, acc2 = acc0, acc3 = acc0;
    for (int k0 = 0; k0 < K; k0 += 32) {
        short8 a  = *(const short8*)(Ap + k0);
        short8 b0 = *(const short8*)(Wp + k0);
        short8 b1 = *(const short8*)(Wp + (size_t)16 * K + k0);
        short8 b2 = *(const short8*)(Wp + (size_t)32 * K + k0);
        short8 b3 = *(const short8*)(Wp + (size_t)48 * K + k0);
        acc0 = __builtin_amdgcn_mfma_f32_16x16x32_bf16(a, b0, acc0, 0, 0, 0);
        acc1 = __builtin_amdgcn_mfma_f32_16x16x32_bf16(a, b1, acc1, 0, 0, 0);
        acc2 = __builtin_amdgcn_mfma_f32_16x16x32_bf16(a, b2, acc2, 0, 0, 0);
        acc3 = __builtin_amdgcn_mfma_f32_16x16x32_bf16(a, b3, acc3, 0, 0, 0);
    }
    f32x4 accs[4] = {acc0, acc1, acc2, acc3};
    #pragma unroll
    for (int j = 0; j < 4; ++j) {
        int n = nb + j * 16 + la;
        float bv = bias[n];
        if (EPI == 2) {
            int mb = m0 + lb * 4;
            int t = mb >> 5, b0i = mb & 31;
            sshort4 pk;
            #pragma unroll
            for (int r = 0; r < 4; ++r) pk[r] = f2bf(accs[j][r] + bv);
            *(sshort4*)(outB + (((size_t)t * 4096 + n) << 5) + b0i) = pk;
        } else {
            #pragma unroll
            for (int r = 0; r < 4; ++r) {
                int m = m0 + lb * 4 + r;
                float v = accs[j][r] + bv;
                if (EPI == 0) outF[(size_t)m * N + n] = v;
                else          outB[(size_t)m * N + n] = f2bf(fmaxf(v, 0.f));
            }
        }
    }
}

// ---------------- flag-dataflow bidirectional LSTM (16 blocks x 512 thr) ----------------
// dir = bid>>3, jsl = bid&7 (64 j's per block, 8 waves x 8 j). Weights in regs
// (2x16 short8/lane). h staged once per block into XOR-swizzled LDS. Per-WAVE
// flags: producer wave packs its 8 j's, 16B sc0sc1 stores, vmcnt(0), flag.
__global__ void __launch_bounds__(512, 2) k_lstm(const short* __restrict__ xg,
                                                 const short* __restrict__ whh,
                                                 const short* __restrict__ hzero,
                                                 short* __restrict__ hsteps,
                                                 short* __restrict__ rnn,
                                                 int* __restrict__ flags) {
    __shared__ short hlds[32][512];      // 32 KiB, 16B-chunk XOR swizzle
    __shared__ short hpack[8][32][8];    // 4 KiB, per-wave pack
    int tid = threadIdx.x;
    int w = tid >> 6, l = tid & 63;
    int la = l & 15, lb = l >> 4;
    int bid = blockIdx.x;
    int dir = bid >> 3, jsl = bid & 7;
    int jw = jsl * 64 + w * 8;
    int wid = jsl * 8 + w;               // wave id within dir, 0..63
    int jj = la & 7;
    // gate-row for B-frag tile n: out-col = n*16+la -> gate = (n*16+la)>>3
    int grow0 = dir * 2048 + ((la >> 3) + 0) * 512 + jw + jj;   // gates 0/1 (i,f)
    int grow1 = dir * 2048 + ((la >> 3) + 2) * 512 + jw + jj;   // gates 2/3 (g,o)

    // weight B-fragments in registers
    short8 wf0[16], wf1[16];
    {
        const short* wr0 = whh + (size_t)grow0 * 512 + lb * 8;
        const short* wr1 = whh + (size_t)grow1 * 512 + lb * 8;
        #pragma unroll
        for (int ks = 0; ks < 16; ++ks) {
            wf0[ks] = *(const short8*)(wr0 + ks * 32);
            wf1[ks] = *(const short8*)(wr1 + ks * 32);
        }
    }

    // staging addresses (thread stages 64 contiguous bytes of h)
    const int strow = tid >> 4, stc0 = (tid & 15) * 4;
    char* stdst = (char*)&hlds[0][0] + strow * 1024;
    const int stswz = (strow & 7) << 4;
    // ds_read addresses for A-frags (rows la and la+16; same swizzle bits)
    const char* arow0 = (const char*)&hlds[0][0] + la * 1024;
    const char* arow1 = arow0 + 16 * 1024;
    const int aswz = (la & 7) << 4;

    float cst[2][4] = {{0.f,0.f,0.f,0.f},{0.f,0.f,0.f,0.f}};

    for (int s = 0; s < T_; ++s) {
        int t = dir ? (T_ - 1 - s) : s;
        const short* hb = (s == 0) ? hzero
                                   : (hsteps + ((size_t)(dir * T_ + (s - 1)) << 14));
        short* hn = hsteps + ((size_t)(dir * T_ + s) << 14);

        // xg loads (plain cached), issued first. Batch stride = 1 short;
        // mt=1 tile needs b += 16 shorts = +32 BYTES.
        ull xq[4];
        {
            const short* x0p = xg + (size_t)t * 131072 + (size_t)grow0 * 32 + lb * 4;
            const short* x1p = xg + (size_t)t * 131072 + (size_t)grow1 * 32 + lb * 4;
            asm volatile("global_load_dwordx2 %0, %1, off" : "=v"(xq[0]) : "v"(x0p));
            asm volatile("global_load_dwordx2 %0, %1, off offset:32" : "=v"(xq[1]) : "v"(x0p));
            asm volatile("global_load_dwordx2 %0, %1, off" : "=v"(xq[2]) : "v"(x1p));
            asm volatile("global_load_dwordx2 %0, %1, off offset:32" : "=v"(xq[3]) : "v"(x1p));
        }

        // wait for all 64 producer waves of this dir, step s-1
        if (s > 0) {
            const int* fp = flags + (dir * T_ + (s - 1)) * 64;
            int tries = 0;
            while (true) {
                int f;
                asm volatile("global_load_dword %0, %1, off sc0 sc1\n\ts_waitcnt vmcnt(0)"
                             : "=v"(f) : "v"(fp + l) : "memory");
                if (__ballot(f != 0) == ~0ull) break;
                if (++tries > (1 << 20)) break;   // escape: wrong answer, not hang
            }
        }
        __builtin_amdgcn_sched_barrier(0);

        // stage this wave's 1/8 of h (64B/thread) into swizzled LDS
        {
            u32x4 v0, v1, v2, v3;
            const char* src = (const char*)hb + tid * 64;
            LDX4(v0, src, "0"); LDX4(v1, src, "16"); LDX4(v2, src, "32"); LDX4(v3, src, "48");
            asm volatile("s_waitcnt vmcnt(0)" ::: "memory");
            __builtin_amdgcn_sched_barrier(0);
            *(u32x4*)(stdst + (((stc0 + 0) * 16) ^ stswz)) = v0;
            *(u32x4*)(stdst + (((stc0 + 1) * 16) ^ stswz)) = v1;
            *(u32x4*)(stdst + (((stc0 + 2) * 16) ^ stswz)) = v2;
            *(u32x4*)(stdst + (((stc0 + 3) * 16) ^ stswz)) = v3;
        }
        __syncthreads();

        // MFMA: 32 ds_read_b128 + 64 mfma, 4 independent acc chains
        f32x4 acc00 = {0.f,0.f,0.f,0.f}, acc01 = acc00, acc10 = acc00, acc11 = acc00;
        #pragma unroll
        for (int ks = 0; ks < 16; ++ks) {
            int off = ((ks * 64) + lb * 16) ^ aswz;
            short8 a0 = *(const short8*)(arow0 + off);
            short8 a1 = *(const short8*)(arow1 + off);
            acc00 = __builtin_amdgcn_mfma_f32_16x16x32_bf16(a0, wf0[ks], acc00, 0, 0, 0);
            acc01 = __builtin_amdgcn_mfma_f32_16x16x32_bf16(a0, wf1[ks], acc01, 0, 0, 0);
            acc10 = __builtin_amdgcn_mfma_f32_16x16x32_bf16(a1, wf0[ks], acc10, 0, 0, 0);
            acc11 = __builtin_amdgcn_mfma_f32_16x16x32_bf16(a1, wf1[ks], acc11, 0, 0, 0);
        }
        __syncthreads();   // all waves done reading hlds (next stage may overwrite)

        // gates: lanes la<8 own (j=jw+la); partner la^8 supplies f,o
        #pragma unroll
        for (int mt = 0; mt < 2; ++mt) {
            f32x4 accA = mt ? acc10 : acc00;
            f32x4 accB = mt ? acc11 : acc01;
            ull xg0 = xq[mt], xg1 = xq[2 + mt];
            #pragma unroll
            for (int r = 0; r < 4; ++r) {
                float v0 = accA[r] + bf2f((unsigned short)((xg0 >> (16 * r)) & 0xffffu));
                float v1 = accB[r] + bf2f((unsigned short)((xg1 >> (16 * r)) & 0xffffu));
                float s0 = 1.f / (1.f + __expf(-v0));                       // i (la<8) | f
                float s1 = (la < 8) ? (1.f - 2.f / (1.f + __expf(2.f * v1)))  // g
                                    : (1.f / (1.f + __expf(-v1)));            // o
                float f_ = __shfl_xor(s0, 8);
                float o_ = __shfl_xor(s1, 8);
                if (la < 8) {
                    float c = f_ * cst[mt][r] + s0 * s1;
                    cst[mt][r] = c;
                    float h = o_ * (1.f - 2.f / (1.f + __expf(2.f * c)));
                    hpack[w][mt * 16 + lb * 4 + r][la] = f2bf(h);
                }
            }
        }
        asm volatile("s_waitcnt lgkmcnt(0)" ::: "memory");
        __builtin_amdgcn_sched_barrier(0);
        __builtin_amdgcn_wave_barrier();

        // pack-store this wave's 8 j's (16B per b-row), ack, flag, rnn
        u32x4 pk = {0,0,0,0};
        if (l < 32) {
            pk = *(const u32x4*)&hpack[w][l][0];
            short* hp = hn + (size_t)l * 512 + jw;
            asm volatile("global_store_dwordx4 %0, %1, off sc0 sc1" :: "v"(hp), "v"(pk) : "memory");
        }
        asm volatile("s_waitcnt vmcnt(0)" ::: "memory");
        if (l == 0) {
            int one = 1;
            asm volatile("global_store_dword %0, %1, off sc0 sc1"
                         :: "v"(flags + (dir * T_ + s) * 64 + wid), "v"(one) : "memory");
        }
        if (l < 32)
            *(u32x4*)(rnn + ((size_t)l * T_ + t) * 1024 + dir * 512 + jw) = pk;
    }
}

// ---------------- LayerNorm (wave per row of 512) ----------------
__global__ void k_ln(const float* __restrict__ h2, const float* __restrict__ gam,
                     const float* __restrict__ bet, float* __restrict__ tr) {
    int w = threadIdx.x >> 6, l = threadIdx.x & 63;
    size_t row = (size_t)blockIdx.x * 4 + w;
    const float* x = h2 + row * 512;
    float v[8], s = 0.f, s2 = 0.f;
    #pragma unroll
    for (int i = 0; i < 8; ++i) { v[i] = x[l + 64 * i]; s += v[i]; s2 += v[i] * v[i]; }
    #pragma unroll
    for (int off = 32; off; off >>= 1) { s += __shfl_xor(s, off); s2 += __shfl_xor(s2, off); }
    float mu = s * (1.f / 512.f);
    float var = s2 * (1.f / 512.f) - mu * mu;
    float rstd = 1.f / sqrtf(var + 1e-5f);
    float* o = tr + row * 512;
    #pragma unroll
    for (int i = 0; i < 8; ++i) { int k = l + 64 * i; o[k] = (v[i] - mu) * rstd * gam[k] + bet[k]; }
}

// ---------------- cumsum over t (block per batch, thread per feature) ----------------
__global__ void k_cumsum(const float* __restrict__ tr, float* __restrict__ cs) {
    int b = blockIdx.x, f = threadIdx.x;  // 512 threads
    cs[((size_t)b * 121) * 512 + f] = 0.f;
    const float* src = tr + ((size_t)b * 120) * 512 + f;
    float* dst = cs + ((size_t)b * 121 + 1) * 512 + f;
    float run = 0.f;
    for (int t0 = 0; t0 < 120; t0 += 8) {
        float v[8];
        #pragma unroll
        for (int i = 0; i < 8; ++i) v[i] = src[(size_t)(t0 + i) * 512];
        #pragma unroll
        for (int i = 0; i < 8; ++i) { run += v[i]; dst[(size_t)(t0 + i) * 512] = run; }
    }
}

// ---------------- spans + label GEMM (wave per span) ----------------
__global__ void __launch_bounds__(256) k_span(const float* __restrict__ cs,
                                              const float* __restrict__ lw,
                                              const float* __restrict__ lbias,
                                              float* __restrict__ out) {
    __shared__ float wl[20][512];
    for (int idx = threadIdx.x; idx < 20 * 512; idx += 256) {
        int c = idx >> 9, k = idx & 511;
        wl[c][k] = lw[(size_t)k * 20 + c];
    }
    __syncthreads();
    int w = threadIdx.x >> 6, l = threadIdx.x & 63;
    int nw = gridDim.x * 4;
    for (int sp = blockIdx.x * 4 + w; sp < NSPAN; sp += nw) {
        int b = sp / 1155, s = sp - b * 1155;
        int beg, len;
        if (s < 1110) { beg = s / 10; len = s - beg * 10 + 1; }
        else {
            int t2 = s - 1110; beg = 111; int ll = 9;
            while (t2 >= ll) { t2 -= ll; --ll; ++beg; }
            len = t2 + 1;
        }
        int end = beg + len;
        const float* ce = cs + ((size_t)b * 121 + end) * 512;
        const float* cb = cs + ((size_t)b * 121 + beg) * 512;
        float inv = 1.f / (float)len;
        float p[20];
        #pragma unroll
        for (int c = 0; c < 20; ++c) p[c] = 0.f;
        #pragma unroll
        for (int i = 0; i < 8; ++i) {
            int k = l + 64 * i;
            float d = (ce[k] - cb[k]) * inv;
            #pragma unroll
            for (int c = 0; c < 20; ++c) p[c] += d * wl[c][k];
        }
        #pragma unroll
        for (int off = 32; off; off >>= 1) {
            #pragma unroll
            for (int c = 0; c < 20; ++c) p[c] += __shfl_xor(p[c], off);
        }
        if (l == 0) {
            float* o = out + (size_t)sp * 20;
            #pragma unroll
            for (int c = 0; c < 20; ++c) o[c] = p[c] + lbias[c];
        }
    }
}

// ---------------- column-wise logsumexp over 36960 rows ----------------
__global__ void __launch_bounds__(256) k_lsepart(const float* __restrict__ logits,
                                                 float2* __restrict__ part) {
    float m[20], sm[20];
    #pragma unroll
    for (int c = 0; c < 20; ++c) { m[c] = -1e30f; sm[c] = 0.f; }
    for (int row = blockIdx.x * 256 + threadIdx.x; row < NSPAN; row += gridDim.x * 256) {
        const float* r = logits + (size_t)row * 20;
        #pragma unroll
        for (int c = 0; c < 20; ++c) {
            float x = r[c];
            float nm = fmaxf(m[c], x);
            sm[c] = sm[c] * expf(m[c] - nm) + expf(x - nm);
            m[c] = nm;
        }
    }
    __shared__ float2 red[256][20];
    #pragma unroll
    for (int c = 0; c < 20; ++c) red[threadIdx.x][c] = make_float2(m[c], sm[c]);
    __syncthreads();
    for (int st = 128; st; st >>= 1) {
        if (threadIdx.x < st) {
            #pragma unroll
            for (int c = 0; c < 20; ++c) {
                float2 a = red[threadIdx.x][c], b = red[threadIdx.x + st][c];
                float nm = fmaxf(a.x, b.x);
                float ss = a.y * expf(a.x - nm) + b.y * expf(b.x - nm);
                red[threadIdx.x][c] = make_float2(nm, ss);
            }
        }
        __syncthreads();
    }
    if (threadIdx.x < 20) part[(size_t)blockIdx.x * 20 + threadIdx.x] = red[0][threadIdx.x];
}

__global__ void k_lsefin(const float2* __restrict__ part, int nparts, float* __restrict__ lse) {
    int c = threadIdx.x;
    if (c >= 20) return;
    float m = -1e30f, s = 0.f;
    for (int i = 0; i < nparts; ++i) {
        float2 a = part[(size_t)i * 20 + c];
        float nm = fmaxf(m, a.x);
        s = s * expf(m - nm) + a.y * expf(a.x - nm);
        m = nm;
    }
    lse[c] = m + logf(s);
}

__global__ void k_sub(float* __restrict__ out, const float* __restrict__ lse) {
    int i = blockIdx.x * 256 + threadIdx.x;
    if (i < NSPAN * 20) out[i] -= lse[i % 20];
}

// ---------------- launch ----------------
extern "C" void kernel_launch(void* const* d_in, const int* in_sizes, int n_in,
                              void* d_out, int out_size, void* d_ws, size_t ws_size,
                              hipStream_t stream) {
    (void)in_sizes; (void)n_in; (void)out_size; (void)ws_size;
    const int*   tokens = (const int*)  d_in[0];
    const float* emb    = (const float*)d_in[1];
    const float* w_ih_f = (const float*)d_in[2];
    const float* w_hh_f = (const float*)d_in[3];
    const float* b_ih_f = (const float*)d_in[4];
    const float* b_hh_f = (const float*)d_in[5];
    const float* w_ih_b = (const float*)d_in[6];
    const float* w_hh_b = (const float*)d_in[7];
    const float* b_ih_b = (const float*)d_in[8];
    const float* b_hh_b = (const float*)d_in[9];
    const float* lin1_w = (const float*)d_in[10];
    const float* lin1_b = (const float*)d_in[11];
    const float* lin2_w = (const float*)d_in[12];
    const float* lin2_b = (const float*)d_in[13];
    const float* ln_g   = (const float*)d_in[14];
    const float* ln_b   = (const float*)d_in[15];
    const float* label_w= (const float*)d_in[16];
    const float* label_b= (const float*)d_in[17];
    float* out = (float*)d_out;

    char* ws = (char*)d_ws;
    size_t off = 0;
    auto alloc = [&](size_t bytes) { char* p = ws + off; off += (bytes + 255) & ~size_t(255); return p; };
    // persistent-lifetime regions (~57 MB total; R2's proven-fit was 76.9 MB)
    short*  xbf   = (short*)alloc(3840ull * 256 * 2);
    short*  wihbf = (short*)alloc(4096ull * 256 * 2);
    short*  whhbf = (short*)alloc(2ull * 2048 * 512 * 2);   // dead after k_lstm
    short*  l1wbf = (short*)alloc(512ull * 1024 * 2);
    short*  l2wbf = (short*)alloc(512ull * 512 * 2);
    float*  biasc = (float*)alloc(4096ull * 4);
    short*  xg    = (short*)alloc(120ull * 4096 * 32 * 2);  // dead after k_lstm
    short*  hzero = (short*)alloc(32ull * 512 * 2);
    short*  hsteps= (short*)alloc(2ull * 120 * 32 * 512 * 2); // dead after k_lstm
    short*  rnn   = (short*)alloc(3840ull * 1024 * 2);
    int*    flags = (int*)  alloc(2ull * 120 * 64 * 4);
    float2* part  = (float2*)alloc(120ull * 20 * 8);
    float*  lse   = (float*)alloc(256);
    // overlays onto dead regions (strict stream ordering guarantees safety)
    short*  h1    = (short*)whhbf;          // 3.93 MB <= 4.19 MB, written after k_lstm
    float*  h2    = (float*)hsteps;         // 7.86 MB == 7.86 MB, written after k_lstm
    float*  tr    = (float*)xg;             // 7.86 MB <= 31.4 MB, written after k_lstm
    float*  cs    = (float*)((char*)xg + 8ull * 1024 * 1024);  // 7.93 MB, inside xg

    hipMemsetAsync(hzero, 0x00, 32ull * 512 * 2, stream);
    hipMemsetAsync(flags, 0x00, 2ull * 120 * 64 * 4, stream);

    k_gather<<<3840, 256, 0, stream>>>(tokens, emb, xbf);
    int n8;
    n8 = 2048 * 256 / 8; k_convert<<<(n8 + 255) / 256, 256, 0, stream>>>(w_ih_f, wihbf, n8);
    n8 = 2048 * 256 / 8; k_convert<<<(n8 + 255) / 256, 256, 0, stream>>>(w_ih_b, wihbf + 2048ull * 256, n8);
    n8 = 2048 * 512 / 8; k_convert<<<(n8 + 255) / 256, 256, 0, stream>>>(w_hh_f, whhbf, n8);
    n8 = 2048 * 512 / 8; k_convert<<<(n8 + 255) / 256, 256, 0, stream>>>(w_hh_b, whhbf + 2048ull * 512, n8);
    n8 = 512 * 1024 / 8; k_convert<<<(n8 + 255) / 256, 256, 0, stream>>>(lin1_w, l1wbf, n8);
    n8 = 512 * 512 / 8;  k_convert<<<(n8 + 255) / 256, 256, 0, stream>>>(lin2_w, l2wbf, n8);
    k_biascomb<<<16, 256, 0, stream>>>(b_ih_f, b_hh_f, b_ih_b, b_hh_b, biasc);

    // xg[t][g(4096)][b] = x @ [w_ih_f; w_ih_b]^T + (b_ih + b_hh)
    k_gemm<2><<<dim3(60, 64), 256, 0, stream>>>(xbf, wihbf, biasc, nullptr, xg, 4096, 256);
    // recurrence -> rnn[b*T+t][1024] (fwd | bwd)
    k_lstm<<<16, 512, 0, stream>>>(xg, whhbf, hzero, hsteps, rnn, flags);
    // lin1 + relu -> bf16   (h1 overlays whhbf)
    k_gemm<1><<<dim3(60, 8), 256, 0, stream>>>(rnn, l1wbf, lin1_b, nullptr, h1, 512, 1024);
    // lin2 -> fp32          (h2 overlays hsteps)
    k_gemm<0><<<dim3(60, 8), 256, 0, stream>>>(h1, l2wbf, lin2_b, h2, nullptr, 512, 512);
    k_ln<<<960, 256, 0, stream>>>(h2, ln_g, ln_b, tr);
    k_cumsum<<<32, 512, 0, stream>>>(tr, cs);
    k_span<<<512, 256, 0, stream>>>(cs, label_w, label_b, out);
    k_lsepart<<<120, 256, 0, stream>>>(out, part);
    k_lsefin<<<1, 32, 0, stream>>>(part, 120, lse);
    k_sub<<<(NSPAN * 20 + 255) / 256, 256, 0, stream>>>(out, lse);
}

// Round 9
// 937.429 us; speedup vs baseline: 1.2981x; 1.2981x over previous
//
#include <hip/hip_runtime.h>

#define B_ 32
#define T_ 120
#define E_ 256
#define H_ 512
#define NSPAN 36960   // B_ * 1155

typedef __attribute__((ext_vector_type(8))) short short8;
typedef __attribute__((ext_vector_type(4))) short sshort4;
typedef __attribute__((ext_vector_type(4))) float f32x4;
typedef __attribute__((ext_vector_type(4))) unsigned int u32x4;
typedef unsigned long long ull;

__device__ __forceinline__ short f2bf(float x) {
    union { float f; unsigned u; } v; v.f = x;
    unsigned r = v.u + 0x7fffu + ((v.u >> 16) & 1u);
    return (short)(r >> 16);
}
__device__ __forceinline__ float bf2f(unsigned short x) {
    union { unsigned u; float f; } v; v.u = ((unsigned)x) << 16;
    return v.f;
}

// coherent (IC-visible) 16B load, runtime address
#define LDC(dst, addr) \
    asm volatile("global_load_dwordx4 %0, %1, off sc0 sc1" : "=v"(dst) : "v"(addr))

// ---------------- gather tokens -> x bf16 (row m = t*32 + b) ----------------
__global__ void k_gather(const int* __restrict__ tokens, const float* __restrict__ emb,
                         short* __restrict__ xbf) {
    int m = blockIdx.x;              // 0..3839, m = t*32+b
    int t = m >> 5, b = m & 31;
    int tok = tokens[b * T_ + t];
    int e = threadIdx.x;             // 256
    xbf[(size_t)m * E_ + e] = f2bf(emb[(size_t)tok * E_ + e]);
}

// ---------------- fp32 -> bf16 convert ----------------
__global__ void k_convert(const float* __restrict__ src, short* __restrict__ dst, int n8) {
    int i = blockIdx.x * blockDim.x + threadIdx.x;
    if (i >= n8) return;
    const float4* s4 = (const float4*)src + (size_t)i * 2;
    float4 a = s4[0], b = s4[1];
    short8 o;
    o[0]=f2bf(a.x); o[1]=f2bf(a.y); o[2]=f2bf(a.z); o[3]=f2bf(a.w);
    o[4]=f2bf(b.x); o[5]=f2bf(b.y); o[6]=f2bf(b.z); o[7]=f2bf(b.w);
    *(short8*)(dst + (size_t)i * 8) = o;
}

__global__ void k_biascomb(const float* __restrict__ bf1, const float* __restrict__ bf2,
                           const float* __restrict__ bb1, const float* __restrict__ bb2,
                           float* __restrict__ out) {
    int i = blockIdx.x * 256 + threadIdx.x;   // 4096
    out[i] = (i < 2048) ? (bf1[i] + bf2[i]) : (bb1[i - 2048] + bb2[i - 2048]);
}

// ---------------- generic bf16 MFMA GEMM: out = A(MxK) @ W(NxK)^T + bias ----------------
template <int EPI>
__global__ void __launch_bounds__(256) k_gemm(const short* __restrict__ A,
                                              const short* __restrict__ W,
                                              const float* __restrict__ bias,
                                              float* __restrict__ outF,
                                              short* __restrict__ outB,
                                              int N, int K) {
    int w = threadIdx.x >> 6, l = threadIdx.x & 63;
    int la = l & 15, lb = l >> 4;
    int m0 = blockIdx.x * 64 + w * 16;
    int nb = blockIdx.y * 64;
    const short* Ap = A + (size_t)(m0 + la) * K + lb * 8;
    const short* Wp = W + (size_t)(nb + la) * K + lb * 8;
    f32x4 acc0 = {0.f,0.f,0.f,0.f}, acc1 = acc0, acc2 = acc0, acc3 = acc0;
    for (int k0 = 0; k0 < K; k0 += 32) {
        short8 a  = *(const short8*)(Ap + k0);
        short8 b0 = *(const short8*)(Wp + k0);
        short8 b1 = *(const short8*)(Wp + (size_t)16 * K + k0);
        short8 b2 = *(const short8*)(Wp + (size_t)32 * K + k0);
        short8 b3 = *(const short8*)(Wp + (size_t)48 * K + k0);
        acc0 = __builtin_amdgcn_mfma_f32_16x16x32_bf16(a, b0, acc0, 0, 0, 0);
        acc1 = __builtin_amdgcn_mfma_f32_16x16x32_bf16(a, b1, acc1, 0, 0, 0);
        acc2 = __builtin_amdgcn_mfma_f32_16x16x32_bf16(a, b2, acc2, 0, 0, 0);
        acc3 = __builtin_amdgcn_mfma_f32_16x16x32_bf16(a, b3, acc3, 0, 0, 0);
    }
    f32x4 accs[4] = {acc0, acc1, acc2, acc3};
    #pragma unroll
    for (int j = 0; j < 4; ++j) {
        int n = nb + j * 16 + la;
        float bv = bias[n];
        if (EPI == 2) {
            int mb = m0 + lb * 4;
            int t = mb >> 5, b0i = mb & 31;
            sshort4 pk;
            #pragma unroll
            for (int r = 0; r < 4; ++r) pk[r] = f2bf(accs[j][r] + bv);
            *(sshort4*)(outB + (((size_t)t * 4096 + n) << 5) + b0i) = pk;
        } else {
            #pragma unroll
            for (int r = 0; r < 4; ++r) {
                int m = m0 + lb * 4 + r;
                float v = accs[j][r] + bv;
                if (EPI == 0) outF[(size_t)m * N + n] = v;
                else          outB[(size_t)m * N + n] = f2bf(fmaxf(v, 0.f));
            }
        }
    }
}

// ---------------- sentinel-dataflow bidirectional LSTM (R2 structure) ----------------
// 64 blocks x 256 thr: dir = bid>>5, jsl = bid&31 (16 j's). Weights in LDS
// (swizzled). Sync is fused into the data: per-step h buffers pre-armed with
// 0xFF (bf16 NaN, unreachable by real h); producers fire packed 8B write-through
// stores (no ack/flag/atomic); consumers stage 32KB and retry dirty chunks.
__global__ void __launch_bounds__(256, 1) k_lstm(const short* __restrict__ xg,
                                                 const short* __restrict__ whh,
                                                 const short* __restrict__ hzero,
                                                 short* __restrict__ hsteps,
                                                 short* __restrict__ rnn) {
    __shared__ short wlds[4][16][512];   // 64 KiB
    __shared__ short hlds[32][512];      // 32 KiB
    __shared__ short hpack[4][32][4];    // 1 KiB
    int tid = threadIdx.x;
    int w = tid >> 6, l = tid & 63;
    int la = l & 15, lb = l >> 4;
    int bid = blockIdx.x;
    int dir = bid >> 5, jsl = bid & 31;
    int jw = jsl * 16 + w * 4;

    // stage weights, swizzled: row rr at byte rr*1024, chunk c16 at (c16*16)^((rr&7)<<4)
    {
        char* base = (char*)&wlds[w][0][0];
        for (int cc = l; cc < 1024; cc += 64) {
            int rr = cc >> 6, c16 = cc & 63;
            int gate = rr >> 2, jj = rr & 3;
            short8 v = *(const short8*)(whh + ((size_t)dir * 2048 + gate * 512 + jw + jj) * 512 + c16 * 8);
            *(short8*)(base + rr * 1024 + ((c16 * 16) ^ ((rr & 7) << 4))) = v;
        }
    }
    __syncthreads();

    float cst[2][4] = {{0.f,0.f,0.f,0.f},{0.f,0.f,0.f,0.f}};
    int gate = la >> 2;
    int grow = dir * 2048 + gate * 512 + jw + (la & 3);
    const char* wrow = (const char*)&wlds[w][0][0] + la * 1024;
    const char* hrow0 = (const char*)&hlds[0][0] + la * 1024;
    const char* hrow1 = hrow0 + 16 * 1024;
    int swz = (la & 7) << 4;

    for (int s = 0; s < T_; ++s) {
        int t = dir ? (T_ - 1 - s) : s;
        const short* hb = (s == 0) ? hzero
                                   : (hsteps + ((size_t)(dir * T_ + (s - 1)) << 14));
        short* hn = hsteps + ((size_t)(dir * T_ + s) << 14);

        // stage h (32 KB/block) with sentinel verification; xg loads overlapped
        ull x0, x1;
        {
            u32x4 vv[8];
            const char* src = (const char*)hb;
            #pragma unroll
            for (int i = 0; i < 8; ++i)
                LDC(vv[i], src + (tid + 256 * i) * 16);
            const short* xgp = xg + ((size_t)t * 4096 + grow) * 32;
            x0 = *(const ull*)(xgp + lb * 4);
            x1 = *(const ull*)(xgp + 16 + lb * 4);
            asm volatile("s_waitcnt vmcnt(0)" ::: "memory");
            __builtin_amdgcn_sched_barrier(0);
            // each 16B chunk = two independent 8B producer stores: check [0],[2]
            int tries = 0;
            while (true) {
                unsigned bad = 0;
                #pragma unroll
                for (int i = 0; i < 8; ++i)
                    if (vv[i][0] == 0xFFFFFFFFu || vv[i][2] == 0xFFFFFFFFu) bad |= 1u << i;
                if (!__any(bad != 0)) break;
                if (++tries > (1 << 17)) break;   // escape: wrong answer, not hang
                #pragma unroll
                for (int i = 0; i < 8; ++i)
                    if (bad & (1u << i)) LDC(vv[i], src + (tid + 256 * i) * 16);
                asm volatile("s_waitcnt vmcnt(0)" ::: "memory");
                __builtin_amdgcn_sched_barrier(0);
            }
            char* hdst = (char*)&hlds[0][0];
            #pragma unroll
            for (int i = 0; i < 8; ++i) {
                int byte = (tid + 256 * i) << 4;
                int row = byte >> 10, col = byte & 1023;
                *(u32x4*)(hdst + row * 1024 + (col ^ ((row & 7) << 4))) = vv[i];
            }
        }
        __syncthreads();

        float xv[2][4];
        #pragma unroll
        for (int r = 0; r < 4; ++r) {
            xv[0][r] = bf2f((unsigned short)((x0 >> (16 * r)) & 0xffffu));
            xv[1][r] = bf2f((unsigned short)((x1 >> (16 * r)) & 0xffffu));
        }

        f32x4 a0A = {0.f,0.f,0.f,0.f}, a0B = a0A, a1A = a0A, a1B = a0A;
        #pragma unroll
        for (int ks2 = 0; ks2 < 8; ++ks2) {
            int co0 = ((ks2 * 128) + lb * 16) ^ swz;
            int co1 = co0 ^ 64;
            short8 wA = *(const short8*)(wrow + co0);
            short8 wB = *(const short8*)(wrow + co1);
            short8 h0A = *(const short8*)(hrow0 + co0);
            short8 h0B = *(const short8*)(hrow0 + co1);
            short8 h1A = *(const short8*)(hrow1 + co0);
            short8 h1B = *(const short8*)(hrow1 + co1);
            a0A = __builtin_amdgcn_mfma_f32_16x16x32_bf16(h0A, wA, a0A, 0, 0, 0);
            a1A = __builtin_amdgcn_mfma_f32_16x16x32_bf16(h1A, wA, a1A, 0, 0, 0);
            a0B = __builtin_amdgcn_mfma_f32_16x16x32_bf16(h0B, wB, a0B, 0, 0, 0);
            a1B = __builtin_amdgcn_mfma_f32_16x16x32_bf16(h1B, wB, a1B, 0, 0, 0);
        }
        __syncthreads();   // all waves done reading hlds before next stage overwrites
        f32x4 a0 = a0A + a0B, a1 = a1A + a1B;

        float val[2][4];
        #pragma unroll
        for (int mt = 0; mt < 2; ++mt) {
            #pragma unroll
            for (int r = 0; r < 4; ++r) {
                float x = (mt ? a1[r] : a0[r]) + xv[mt][r];
                val[mt][r] = (gate == 2) ? (1.f - 2.f / (1.f + __expf(2.f * x)))
                                         : (1.f / (1.f + __expf(-x)));
            }
        }

        #pragma unroll
        for (int mt = 0; mt < 2; ++mt) {
            #pragma unroll
            for (int r = 0; r < 4; ++r) {
                float v = val[mt][r];
                float vf = __shfl_xor(v, 4);
                float vg = __shfl_xor(v, 8);
                float vo = __shfl_xor(v, 12);
                if (la < 4) {   // gate-0 lanes: v=sig(i), vf=sig(f), vg=tanh(g), vo=sig(o)
                    float c = vf * cst[mt][r] + v * vg;
                    cst[mt][r] = c;
                    float h = vo * (1.f - 2.f / (1.f + __expf(2.f * c)));
                    hpack[w][mt * 16 + lb * 4 + r][la] = f2bf(h);
                }
            }
        }
        asm volatile("s_waitcnt lgkmcnt(0)" ::: "memory");
        __builtin_amdgcn_sched_barrier(0);
        __builtin_amdgcn_wave_barrier();

        // fire-and-forget packed 8B write-through store; rnn plain store
        if (l < 32) {
            ull pk = *(const ull*)&hpack[w][l][0];
            short* hp = hn + (size_t)l * 512 + jw;
            asm volatile("global_store_dwordx2 %0, %1, off sc0 sc1" :: "v"(hp), "v"(pk) : "memory");
            *(ull*)(rnn + ((size_t)l * T_ + t) * 1024 + dir * 512 + jw) = pk;
        }
        __builtin_amdgcn_wave_barrier();
    }
}

// ---------------- LayerNorm (wave per row of 512) ----------------
__global__ void k_ln(const float* __restrict__ h2, const float* __restrict__ gam,
                     const float* __restrict__ bet, float* __restrict__ tr) {
    int w = threadIdx.x >> 6, l = threadIdx.x & 63;
    size_t row = (size_t)blockIdx.x * 4 + w;
    const float* x = h2 + row * 512;
    float v[8], s = 0.f, s2 = 0.f;
    #pragma unroll
    for (int i = 0; i < 8; ++i) { v[i] = x[l + 64 * i]; s += v[i]; s2 += v[i] * v[i]; }
    #pragma unroll
    for (int off = 32; off; off >>= 1) { s += __shfl_xor(s, off); s2 += __shfl_xor(s2, off); }
    float mu = s * (1.f / 512.f);
    float var = s2 * (1.f / 512.f) - mu * mu;
    float rstd = 1.f / sqrtf(var + 1e-5f);
    float* o = tr + row * 512;
    #pragma unroll
    for (int i = 0; i < 8; ++i) { int k = l + 64 * i; o[k] = (v[i] - mu) * rstd * gam[k] + bet[k]; }
}

// ---------------- cumsum over t (block per batch, thread per feature) ----------------
__global__ void k_cumsum(const float* __restrict__ tr, float* __restrict__ cs) {
    int b = blockIdx.x, f = threadIdx.x;  // 512 threads
    cs[((size_t)b * 121) * 512 + f] = 0.f;
    const float* src = tr + ((size_t)b * 120) * 512 + f;
    float* dst = cs + ((size_t)b * 121 + 1) * 512 + f;
    float run = 0.f;
    for (int t0 = 0; t0 < 120; t0 += 8) {
        float v[8];
        #pragma unroll
        for (int i = 0; i < 8; ++i) v[i] = src[(size_t)(t0 + i) * 512];
        #pragma unroll
        for (int i = 0; i < 8; ++i) { run += v[i]; dst[(size_t)(t0 + i) * 512] = run; }
    }
}

// ---------------- spans + label GEMM (wave per span) ----------------
__global__ void __launch_bounds__(256) k_span(const float* __restrict__ cs,
                                              const float* __restrict__ lw,
                                              const float* __restrict__ lbias,
                                              float* __restrict__ out) {
    __shared__ float wl[20][512];
    for (int idx = threadIdx.x; idx < 20 * 512; idx += 256) {
        int c = idx >> 9, k = idx & 511;
        wl[c][k] = lw[(size_t)k * 20 + c];
    }
    __syncthreads();
    int w = threadIdx.x >> 6, l = threadIdx.x & 63;
    int nw = gridDim.x * 4;
    for (int sp = blockIdx.x * 4 + w; sp < NSPAN; sp += nw) {
        int b = sp / 1155, s = sp - b * 1155;
        int beg, len;
        if (s < 1110) { beg = s / 10; len = s - beg * 10 + 1; }
        else {
            int t2 = s - 1110; beg = 111; int ll = 9;
            while (t2 >= ll) { t2 -= ll; --ll; ++beg; }
            len = t2 + 1;
        }
        int end = beg + len;
        const float* ce = cs + ((size_t)b * 121 + end) * 512;
        const float* cb = cs + ((size_t)b * 121 + beg) * 512;
        float inv = 1.f / (float)len;
        float p[20];
        #pragma unroll
        for (int c = 0; c < 20; ++c) p[c] = 0.f;
        #pragma unroll
        for (int i = 0; i < 8; ++i) {
            int k = l + 64 * i;
            float d = (ce[k] - cb[k]) * inv;
            #pragma unroll
            for (int c = 0; c < 20; ++c) p[c] += d * wl[c][k];
        }
        #pragma unroll
        for (int off = 32; off; off >>= 1) {
            #pragma unroll
            for (int c = 0; c < 20; ++c) p[c] += __shfl_xor(p[c], off);
        }
        if (l == 0) {
            float* o = out + (size_t)sp * 20;
            #pragma unroll
            for (int c = 0; c < 20; ++c) o[c] = p[c] + lbias[c];
        }
    }
}

// ---------------- column-wise logsumexp over 36960 rows ----------------
__global__ void __launch_bounds__(256) k_lsepart(const float* __restrict__ logits,
                                                 float2* __restrict__ part) {
    float m[20], sm[20];
    #pragma unroll
    for (int c = 0; c < 20; ++c) { m[c] = -1e30f; sm[c] = 0.f; }
    for (int row = blockIdx.x * 256 + threadIdx.x; row < NSPAN; row += gridDim.x * 256) {
        const float* r = logits + (size_t)row * 20;
        #pragma unroll
        for (int c = 0; c < 20; ++c) {
            float x = r[c];
            float nm = fmaxf(m[c], x);
            sm[c] = sm[c] * expf(m[c] - nm) + expf(x - nm);
            m[c] = nm;
        }
    }
    __shared__ float2 red[256][20];
    #pragma unroll
    for (int c = 0; c < 20; ++c) red[threadIdx.x][c] = make_float2(m[c], sm[c]);
    __syncthreads();
    for (int st = 128; st; st >>= 1) {
        if (threadIdx.x < st) {
            #pragma unroll
            for (int c = 0; c < 20; ++c) {
                float2 a = red[threadIdx.x][c], b = red[threadIdx.x + st][c];
                float nm = fmaxf(a.x, b.x);
                float ss = a.y * expf(a.x - nm) + b.y * expf(b.x - nm);
                red[threadIdx.x][c] = make_float2(nm, ss);
            }
        }
        __syncthreads();
    }
    if (threadIdx.x < 20) part[(size_t)blockIdx.x * 20 + threadIdx.x] = red[0][threadIdx.x];
}

__global__ void k_lsefin(const float2* __restrict__ part, int nparts, float* __restrict__ lse) {
    int c = threadIdx.x;
    if (c >= 20) return;
    float m = -1e30f, s = 0.f;
    for (int i = 0; i < nparts; ++i) {
        float2 a = part[(size_t)i * 20 + c];
        float nm = fmaxf(m, a.x);
        s = s * expf(m - nm) + a.y * expf(a.x - nm);
        m = nm;
    }
    lse[c] = m + logf(s);
}

__global__ void k_sub(float* __restrict__ out, const float* __restrict__ lse) {
    int i = blockIdx.x * 256 + threadIdx.x;
    if (i < NSPAN * 20) out[i] -= lse[i % 20];
}

// ---------------- launch ----------------
extern "C" void kernel_launch(void* const* d_in, const int* in_sizes, int n_in,
                              void* d_out, int out_size, void* d_ws, size_t ws_size,
                              hipStream_t stream) {
    (void)in_sizes; (void)n_in; (void)out_size; (void)ws_size;
    const int*   tokens = (const int*)  d_in[0];
    const float* emb    = (const float*)d_in[1];
    const float* w_ih_f = (const float*)d_in[2];
    const float* w_hh_f = (const float*)d_in[3];
    const float* b_ih_f = (const float*)d_in[4];
    const float* b_hh_f = (const float*)d_in[5];
    const float* w_ih_b = (const float*)d_in[6];
    const float* w_hh_b = (const float*)d_in[7];
    const float* b_ih_b = (const float*)d_in[8];
    const float* b_hh_b = (const float*)d_in[9];
    const float* lin1_w = (const float*)d_in[10];
    const float* lin1_b = (const float*)d_in[11];
    const float* lin2_w = (const float*)d_in[12];
    const float* lin2_b = (const float*)d_in[13];
    const float* ln_g   = (const float*)d_in[14];
    const float* ln_b   = (const float*)d_in[15];
    const float* label_w= (const float*)d_in[16];
    const float* label_b= (const float*)d_in[17];
    float* out = (float*)d_out;

    char* ws = (char*)d_ws;
    size_t off = 0;
    auto alloc = [&](size_t bytes) { char* p = ws + off; off += (bytes + 255) & ~size_t(255); return p; };
    // persistent-lifetime regions (~57 MB total; R2's proven-fit was 76.9 MB)
    short*  xbf   = (short*)alloc(3840ull * 256 * 2);
    short*  wihbf = (short*)alloc(4096ull * 256 * 2);
    short*  whhbf = (short*)alloc(2ull * 2048 * 512 * 2);   // dead after k_lstm
    short*  l1wbf = (short*)alloc(512ull * 1024 * 2);
    short*  l2wbf = (short*)alloc(512ull * 512 * 2);
    float*  biasc = (float*)alloc(4096ull * 4);
    short*  xg    = (short*)alloc(120ull * 4096 * 32 * 2);  // dead after k_lstm
    short*  hzero = (short*)alloc(32ull * 512 * 2);
    short*  hsteps= (short*)alloc(2ull * 120 * 32 * 512 * 2); // dead after k_lstm
    short*  rnn   = (short*)alloc(3840ull * 1024 * 2);
    float2* part  = (float2*)alloc(120ull * 20 * 8);
    float*  lse   = (float*)alloc(256);
    // overlays onto dead regions (strict stream ordering guarantees safety)
    short*  h1    = (short*)whhbf;          // 3.93 MB <= 4.19 MB, written after k_lstm
    float*  h2    = (float*)hsteps;         // 7.86 MB == 7.86 MB, written after k_lstm
    float*  tr    = (float*)xg;             // 7.86 MB <= 31.4 MB, written after k_lstm
    float*  cs    = (float*)((char*)xg + 8ull * 1024 * 1024);  // 7.93 MB, inside xg

    hipMemsetAsync(hzero, 0x00, 32ull * 512 * 2, stream);
    hipMemsetAsync(hsteps, 0xFF, 2ull * 120 * 32 * 512 * 2, stream);

    k_gather<<<3840, 256, 0, stream>>>(tokens, emb, xbf);
    int n8;
    n8 = 2048 * 256 / 8; k_convert<<<(n8 + 255) / 256, 256, 0, stream>>>(w_ih_f, wihbf, n8);
    n8 = 2048 * 256 / 8; k_convert<<<(n8 + 255) / 256, 256, 0, stream>>>(w_ih_b, wihbf + 2048ull * 256, n8);
    n8 = 2048 * 512 / 8; k_convert<<<(n8 + 255) / 256, 256, 0, stream>>>(w_hh_f, whhbf, n8);
    n8 = 2048 * 512 / 8; k_convert<<<(n8 + 255) / 256, 256, 0, stream>>>(w_hh_b, whhbf + 2048ull * 512, n8);
    n8 = 512 * 1024 / 8; k_convert<<<(n8 + 255) / 256, 256, 0, stream>>>(lin1_w, l1wbf, n8);
    n8 = 512 * 512 / 8;  k_convert<<<(n8 + 255) / 256, 256, 0, stream>>>(lin2_w, l2wbf, n8);
    k_biascomb<<<16, 256, 0, stream>>>(b_ih_f, b_hh_f, b_ih_b, b_hh_b, biasc);

    // xg[t][g(4096)][b] = x @ [w_ih_f; w_ih_b]^T + (b_ih + b_hh)
    k_gemm<2><<<dim3(60, 64), 256, 0, stream>>>(xbf, wihbf, biasc, nullptr, xg, 4096, 256);
    // recurrence -> rnn[b*T+t][1024] (fwd | bwd)
    k_lstm<<<64, 256, 0, stream>>>(xg, whhbf, hzero, hsteps, rnn);
    // lin1 + relu -> bf16   (h1 overlays whhbf)
    k_gemm<1><<<dim3(60, 8), 256, 0, stream>>>(rnn, l1wbf, lin1_b, nullptr, h1, 512, 1024);
    // lin2 -> fp32          (h2 overlays hsteps)
    k_gemm<0><<<dim3(60, 8), 256, 0, stream>>>(h1, l2wbf, lin2_b, h2, nullptr, 512, 512);
    k_ln<<<960, 256, 0, stream>>>(h2, ln_g, ln_b, tr);
    k_cumsum<<<32, 512, 0, stream>>>(tr, cs);
    k_span<<<512, 256, 0, stream>>>(cs, label_w, label_b, out);
    k_lsepart<<<120, 256, 0, stream>>>(out, part);
    k_lsefin<<<1, 32, 0, stream>>>(part, 120, lse);
    k_sub<<<(NSPAN * 20 + 255) / 256, 256, 0, stream>>>(out, lse);
}